// Round 4
// baseline (12204.594 us; speedup 1.0000x reference)
//
#include <hip/hip_runtime.h>
#include <math.h>

#define B_   32
#define S_   1024
#define DIN  512
#define DH   512
#define KTOT 1024          // DH (H part) + DIN (x part)
#define NWG  64
#define TPB  256
#define XST  520           // padded row stride (ushorts) for As_x (512+8)
#define HBQ  4096          // u64 per H buffer: 64 WG x 64 u64 (contiguous per WG)

typedef short short8 __attribute__((ext_vector_type(8)));  // 8 bf16
typedef float f32x4  __attribute__((ext_vector_type(4)));
typedef unsigned long long u64;

__device__ __forceinline__ unsigned short f2bf(float f) {
  unsigned u = __float_as_uint(f);
  u += 0x7FFFu + ((u >> 16) & 1u);   // RNE
  return (unsigned short)(u >> 16);
}
__device__ __forceinline__ float sigmoid_f(float z) { return 1.f / (1.f + __expf(-z)); }
__device__ __forceinline__ float tanh_f(float z) {
  float e = __expf(-2.f * fabsf(z));
  float t = (1.f - e) / (1.f + e);
  return z < 0.f ? -t : t;
}
__device__ __forceinline__ f32x4 mfma16(short8 a, short8 b, f32x4 c) {
  return __builtin_amdgcn_mfma_f32_16x16x32_bf16(a, b, c, 0, 0, 0);
}
__device__ __forceinline__ u64 cload(const u64* p) {
  return __hip_atomic_load(p, __ATOMIC_RELAXED, __HIP_MEMORY_SCOPE_AGENT);
}
__device__ __forceinline__ void cstore(u64* p, u64 v) {
  __hip_atomic_store(p, v, __ATOMIC_RELAXED, __HIP_MEMORY_SCOPE_AGENT);
}

// Rearrange [Wh;Wx] (fp32, per gate) into per-WG B-operand layout, bf16:
// Bws[w][c(0..31)][k(0..1023)], c = gate*8 + j, hcol = 8w + j, k<512 -> Wh, else Wx.
// Also init the 64 publish flags to -1 ("H_{-1} ready", vacuous).
__global__ void k_prep(const float* __restrict__ Whi, const float* __restrict__ Whf,
                       const float* __restrict__ Who, const float* __restrict__ Whc,
                       const float* __restrict__ Wxi, const float* __restrict__ Wxf,
                       const float* __restrict__ Wxo, const float* __restrict__ Wxc,
                       unsigned short* __restrict__ Bws, unsigned* __restrict__ flags) {
  int chunk = blockIdx.x * TPB + threadIdx.x;      // 0..262143, 8 elems each
  int w   = chunk >> 12;
  int rem = chunk & 4095;
  int c   = rem >> 7;
  int k8  = (rem & 127) << 3;
  int g    = c >> 3;
  int hcol = (w << 3) | (c & 7);
  const float* Wh = (g == 0) ? Whi : (g == 1) ? Whf : (g == 2) ? Who : Whc;
  const float* Wx = (g == 0) ? Wxi : (g == 1) ? Wxf : (g == 2) ? Wxo : Wxc;
  short8 sv;
  for (int j = 0; j < 8; ++j) {
    int k = k8 + j;
    float f = (k < DH) ? Wh[(size_t)k * DH + hcol] : Wx[(size_t)(k - DH) * DH + hcol];
    sv[j] = (short)f2bf(f);
  }
  *(short8*)(Bws + (size_t)chunk * 8) = sv;
  if (blockIdx.x == 0 && threadIdx.x < 64)
    flags[threadIdx.x * 4] = 0xFFFFFFFFu;          // -1; 0xAA poison is also negative
}

// Persistent fused LSTM scan. Per step: wave0 polls 64 per-producer flags (1 KB/rnd)
// while waves1-3 stage x_{t+1}; then every lane loads its MFMA A-fragments for the
// H-part DIRECTLY from the producers' contiguous LLC slices (no LDS round-trip);
// MFMA + LDS reduce + gates; wave0 publishes 512B burst + vmcnt drain + 4B flag.
__launch_bounds__(TPB, 1)
__global__ void k_scan(const float* __restrict__ x,
                       const float* __restrict__ bi, const float* __restrict__ bfv,
                       const float* __restrict__ bo, const float* __restrict__ bc,
                       const unsigned short* __restrict__ Bws,
                       u64* __restrict__ hbuf,      // 2 buffers of [64 WG][64 u64]
                       unsigned* __restrict__ flags,// 64 flags, 16B apart
                       float* __restrict__ out) {
  __shared__ unsigned short As_x[2][B_ * XST];   // x_t bf16, double-buffered (66.5 KB)
  __shared__ float R[4 * 64 * 16];               // per-wave partial accumulators (16 KB)
  __shared__ unsigned short Hs[TPB];             // bf16 H staging for packed publish

  const int tid  = threadIdx.x;
  const int w    = blockIdx.x;
  const int lane = tid & 63;
  const int wv   = tid >> 6;                 // wave 0..3 = K-slice owner

  const int eb   = tid >> 3;                 // elementwise: batch 0..31
  const int ej   = tid & 7;                  // elementwise: local hcol 0..7
  const int hcol = (w << 3) | ej;

  const float pbi = bi[hcol], pbf = bfv[hcol], pbo = bo[hcol], pbc = bc[hcol];
  float Creg = 0.f;

  const int r0 = lane & 15;
  const int kq = (lane >> 4) * 8;

  // B fragments -> registers (weights resident for the whole scan)
  short8 bfrag[8][2];
  {
    const int col0 = lane & 15;
    const int kqb  = (lane >> 4) * 8;
    #pragma unroll
    for (int ks = 0; ks < 8; ++ks) {
      int kb = (ks < 4) ? (wv * 128 + ks * 32 + kqb)
                        : (DH + wv * 128 + (ks - 4) * 32 + kqb);
      #pragma unroll
      for (int ni = 0; ni < 2; ++ni) {
        int col = ni * 16 + col0;
        bfrag[ks][ni] = *(const short8*)(Bws + ((size_t)(w * 32 + col) * KTOT + kb));
      }
    }
  }

  // stage x_0 -> As_x[0] (all threads)
  for (int g = tid; g < 4096; g += TPB) {
    int row = g >> 7, cc = g & 127;
    float4 v = *(const float4*)(x + (size_t)row * (S_ * DIN) + cc * 4);
    uint2 p;
    p.x = (unsigned)f2bf(v.x) | ((unsigned)f2bf(v.y) << 16);
    p.y = (unsigned)f2bf(v.z) | ((unsigned)f2bf(v.w) << 16);
    *(uint2*)(&As_x[0][row * XST + cc * 4]) = p;
  }
  __syncthreads();

  // x-part MFMA for t=0
  f32x4 acc00 = {0,0,0,0}, acc01 = {0,0,0,0}, acc10 = {0,0,0,0}, acc11 = {0,0,0,0};
  #pragma unroll
  for (int ks = 0; ks < 4; ++ks) {
    int koff = wv * 128 + ks * 32 + kq;
    short8 a0 = *(const short8*)(&As_x[0][r0 * XST + koff]);
    short8 a1 = *(const short8*)(&As_x[0][(r0 + 16) * XST + koff]);
    acc00 = mfma16(a0, bfrag[4 + ks][0], acc00);
    acc01 = mfma16(a0, bfrag[4 + ks][1], acc01);
    acc10 = mfma16(a1, bfrag[4 + ks][0], acc10);
    acc11 = mfma16(a1, bfrag[4 + ks][1], acc11);
  }

  for (int t = 0; t < S_; ++t) {
    __syncthreads();   // orders prev-iter As_x reads before this iter's staging writes

    // ---- Phase A: wave0 polls flags; waves1-3 stage x_{t+1} ----
    if (wv == 0) {
      if (t > 0) {
        const int target = t - 1;
        int v = (int)__hip_atomic_load(&flags[lane * 4],
                                       __ATOMIC_RELAXED, __HIP_MEMORY_SCOPE_AGENT);
        while (__ballot(v < target)) {
          v = (int)__hip_atomic_load(&flags[lane * 4],
                                     __ATOMIC_RELAXED, __HIP_MEMORY_SCOPE_AGENT);
        }
      }
    } else if (t + 1 < S_) {
      int buf = (t + 1) & 1;
      for (int g = tid - 64; g < 4096; g += 192) {
        int row = g >> 7, cc = g & 127;
        float4 v = *(const float4*)(x + (size_t)row * (S_ * DIN) + (size_t)(t + 1) * DIN + cc * 4);
        uint2 p;
        p.x = (unsigned)f2bf(v.x) | ((unsigned)f2bf(v.y) << 16);
        p.y = (unsigned)f2bf(v.z) | ((unsigned)f2bf(v.w) << 16);
        *(uint2*)(&As_x[buf][row * XST + cc * 4]) = p;
      }
    }
    __syncthreads();

    // ---- Phase B: H-part fragments straight from LLC, then MFMA ----
    if (t > 0) {
      const u64* hr = hbuf + (size_t)((t - 1) & 1) * HBQ;
      union Frag { u64 q[2]; short8 s; };
      Frag fa[4][2];
      #pragma unroll
      for (int ks = 0; ks < 4; ++ks) {
        int gb = (wv * 16 + ks * 4 + (lane >> 4)) * 64;  // producer slice base
        int g0 = gb + r0 * 2;
        int g1 = gb + (r0 + 16) * 2;
        fa[ks][0].q[0] = cload(&hr[g0]);
        fa[ks][0].q[1] = cload(&hr[g0 + 1]);
        fa[ks][1].q[0] = cload(&hr[g1]);
        fa[ks][1].q[1] = cload(&hr[g1 + 1]);
      }
      #pragma unroll
      for (int ks = 0; ks < 4; ++ks) {
        acc00 = mfma16(fa[ks][0].s, bfrag[ks][0], acc00);
        acc01 = mfma16(fa[ks][0].s, bfrag[ks][1], acc01);
        acc10 = mfma16(fa[ks][1].s, bfrag[ks][0], acc10);
        acc11 = mfma16(fa[ks][1].s, bfrag[ks][1], acc11);
      }
    }

    // ---- dump partials for cross-wave reduction ----
    {
      float* rp = &R[(wv * 64 + lane) * 16];
      *(f32x4*)(rp + 0)  = acc00;
      *(f32x4*)(rp + 4)  = acc01;
      *(f32x4*)(rp + 8)  = acc10;
      *(f32x4*)(rp + 12) = acc11;
    }
    __syncthreads();

    // ---- Phase C: elementwise gate math ----
    float pre[4];
    {
      int r = eb & 15, mi = eb >> 4, reg = eb & 3;
      int lq = (r >> 2) * 16;
      #pragma unroll
      for (int g = 0; g < 4; ++g) {
        int c  = g * 8 + ej;
        int ni = c >> 4;
        int ln = (c & 15) + lq;
        int idx = (mi * 2 + ni) * 4 + reg;
        float s = 0.f;
        #pragma unroll
        for (int v = 0; v < 4; ++v) s += R[(v * 64 + ln) * 16 + idx];
        pre[g] = s;
      }
    }
    float I  = sigmoid_f(pre[0] + pbi);
    float F  = sigmoid_f(pre[1] + pbf);
    float O  = sigmoid_f(pre[2] + pbo);
    float Cc = tanh_f(pre[3] + pbc);
    Creg = F * Creg + I * Cc;
    float H = O * tanh_f(Creg);

    out[(size_t)eb * (S_ * DH) + (size_t)t * DH + hcol] = H;
    if (t == S_ - 1) out[(size_t)(B_ * S_ * DH) + eb * DH + hcol] = H;  // Hf
    Hs[tid] = f2bf(H);
    __syncthreads();

    // ---- Phase D: publish (wave0) ----
    if (wv == 0 && t + 1 < S_) {
      int b = lane >> 1, h = lane & 1;
      u64 v = (u64)Hs[b * 8 + h * 4]
            | ((u64)Hs[b * 8 + h * 4 + 1] << 16)
            | ((u64)Hs[b * 8 + h * 4 + 2] << 32)
            | ((u64)Hs[b * 8 + h * 4 + 3] << 48);
      cstore(&hbuf[(size_t)(t & 1) * HBQ + w * 64 + lane], v);
      __builtin_amdgcn_s_waitcnt(0);     // drain data burst to LLC (wave-wide)
      if (lane == 0)
        __hip_atomic_store(&flags[w * 4], (unsigned)t,
                           __ATOMIC_RELAXED, __HIP_MEMORY_SCOPE_AGENT);
    }

    // ---- Phase E: x-part MFMA for t+1 ----
    if (t + 1 < S_) {
      acc00 = (f32x4){0,0,0,0}; acc01 = (f32x4){0,0,0,0};
      acc10 = (f32x4){0,0,0,0}; acc11 = (f32x4){0,0,0,0};
      int buf = (t + 1) & 1;
      #pragma unroll
      for (int ks = 0; ks < 4; ++ks) {
        int koff = wv * 128 + ks * 32 + kq;
        short8 a0 = *(const short8*)(&As_x[buf][r0 * XST + koff]);
        short8 a1 = *(const short8*)(&As_x[buf][(r0 + 16) * XST + koff]);
        acc00 = mfma16(a0, bfrag[4 + ks][0], acc00);
        acc01 = mfma16(a0, bfrag[4 + ks][1], acc01);
        acc10 = mfma16(a1, bfrag[4 + ks][0], acc10);
        acc11 = mfma16(a1, bfrag[4 + ks][1], acc11);
      }
    }
  }
}

extern "C" void kernel_launch(void* const* d_in, const int* in_sizes, int n_in,
                              void* d_out, int out_size, void* d_ws, size_t ws_size,
                              hipStream_t stream) {
  const float* x   = (const float*)d_in[0];
  const float* Wxi = (const float*)d_in[1];
  const float* Whi = (const float*)d_in[2];
  const float* bi  = (const float*)d_in[3];
  const float* Wxf = (const float*)d_in[4];
  const float* Whf = (const float*)d_in[5];
  const float* bfv = (const float*)d_in[6];
  const float* Wxo = (const float*)d_in[7];
  const float* Who = (const float*)d_in[8];
  const float* bo  = (const float*)d_in[9];
  const float* Wxc = (const float*)d_in[10];
  const float* Whc = (const float*)d_in[11];
  const float* bc  = (const float*)d_in[12];
  float* out = (float*)d_out;

  // ws layout: Bws 4 MiB | hbuf 64 KiB (2 buffers) | flags 1 KiB
  unsigned short* Bws   = (unsigned short*)d_ws;
  u64*            hbuf  = (u64*)((char*)d_ws + (size_t)4 * 1024 * 1024);
  unsigned*       flags = (unsigned*)((char*)d_ws + (size_t)4 * 1024 * 1024 + 64 * 1024);

  k_prep<<<1024, TPB, 0, stream>>>(Whi, Whf, Who, Whc, Wxi, Wxf, Wxo, Wxc, Bws, flags);
  k_scan<<<NWG, TPB, 0, stream>>>(x, bi, bfv, bo, bc, Bws, hbuf, flags, out);
}

// Round 5
// 11731.885 us; speedup vs baseline: 1.0403x; 1.0403x over previous
//
#include <hip/hip_runtime.h>
#include <math.h>

#define B_   32
#define S_   1024
#define DIN  512
#define DH   512
#define KTOT 1024          // DH (H part) + DIN (x part)
#define NWG  64
#define TPB  256
#define XST  520           // padded row stride (ushorts) for x tiles (512+8)
#define HST  520           // padded row stride (ushorts) for H tile
#define HBQ  4096          // u64 per H buffer: 64 producers x 64 u64 (contiguous)

typedef short short8 __attribute__((ext_vector_type(8)));  // 8 bf16
typedef float f32x4  __attribute__((ext_vector_type(4)));
typedef unsigned long long u64;

__device__ __forceinline__ unsigned short f2bf(float f) {
  unsigned u = __float_as_uint(f);
  u += 0x7FFFu + ((u >> 16) & 1u);   // RNE
  return (unsigned short)(u >> 16);
}
__device__ __forceinline__ float sigmoid_f(float z) { return 1.f / (1.f + __expf(-z)); }
__device__ __forceinline__ float tanh_f(float z) {
  float e = __expf(-2.f * fabsf(z));
  float t = (1.f - e) / (1.f + e);
  return z < 0.f ? -t : t;
}
__device__ __forceinline__ f32x4 mfma16(short8 a, short8 b, f32x4 c) {
  return __builtin_amdgcn_mfma_f32_16x16x32_bf16(a, b, c, 0, 0, 0);
}
__device__ __forceinline__ u64 cload(const u64* p) {
  return __hip_atomic_load(p, __ATOMIC_RELAXED, __HIP_MEMORY_SCOPE_AGENT);
}
__device__ __forceinline__ void cstore(u64* p, u64 v) {
  __hip_atomic_store(p, v, __ATOMIC_RELAXED, __HIP_MEMORY_SCOPE_AGENT);
}

// Rearrange [Wh;Wx] (fp32, per gate) into per-WG B-operand layout, bf16:
// Bws[w][c(0..31)][k(0..1023)], c = gate*8 + j, hcol = 8w + j, k<512 -> Wh, else Wx.
// Block 1 clears the 64x64 epoch mailbox to -1.
__global__ void k_prep(const float* __restrict__ Whi, const float* __restrict__ Whf,
                       const float* __restrict__ Who, const float* __restrict__ Whc,
                       const float* __restrict__ Wxi, const float* __restrict__ Wxf,
                       const float* __restrict__ Wxo, const float* __restrict__ Wxc,
                       unsigned short* __restrict__ Bws, int* __restrict__ mbox) {
  int chunk = blockIdx.x * TPB + threadIdx.x;      // 0..262143, 8 elems each
  int w   = chunk >> 12;
  int rem = chunk & 4095;
  int c   = rem >> 7;
  int k8  = (rem & 127) << 3;
  int g    = c >> 3;
  int hcol = (w << 3) | (c & 7);
  const float* Wh = (g == 0) ? Whi : (g == 1) ? Whf : (g == 2) ? Who : Whc;
  const float* Wx = (g == 0) ? Wxi : (g == 1) ? Wxf : (g == 2) ? Wxo : Wxc;
  short8 sv;
  for (int j = 0; j < 8; ++j) {
    int k = k8 + j;
    float f = (k < DH) ? Wh[(size_t)k * DH + hcol] : Wx[(size_t)(k - DH) * DH + hcol];
    sv[j] = (short)f2bf(f);
  }
  *(short8*)(Bws + (size_t)chunk * 8) = sv;
  if (blockIdx.x == 1) {
    #pragma unroll
    for (int i = 0; i < 16; ++i) mbox[threadIdx.x * 16 + i] = -1;
  }
}

// Persistent fused LSTM scan. Notification via per-consumer PRIVATE mailboxes:
// producer w stores 512B H-slice burst -> vmcnt(0) drain -> one 64-lane store of
// epoch t into mbox[c][w] for every consumer c. Consumer polls ONLY its own 256B
// mailbox row (exclusive reader -> no writer starvation), then bulk-loads the 32KB
// H exactly once, coalesced. x_{t+1} staged by waves 1-3 during the poll.
__launch_bounds__(TPB, 1)
__global__ void k_scan(const float* __restrict__ x,
                       const float* __restrict__ bi, const float* __restrict__ bfv,
                       const float* __restrict__ bo, const float* __restrict__ bc,
                       const unsigned short* __restrict__ Bws,
                       u64* __restrict__ hbuf,      // 2 buffers of [64][64] u64
                       int* __restrict__ mbox,      // [64 consumers][64 producers]
                       float* __restrict__ out) {
  __shared__ unsigned short As_x[2][B_ * XST];   // x_t bf16, double-buffered (66.5 KB)
  __shared__ unsigned short Ah[B_ * HST];        // H_{t-1} bf16 (33.3 KB)
  __shared__ float R[4 * 64 * 16];               // per-wave partials (16 KB)
  __shared__ unsigned short Hs[TPB];             // bf16 H for packed publish

  const int tid  = threadIdx.x;
  const int w    = blockIdx.x;
  const int lane = tid & 63;
  const int wv   = tid >> 6;                 // wave 0..3 = K-slice owner

  const int eb   = tid >> 3;                 // elementwise: batch 0..31
  const int ej   = tid & 7;                  // elementwise: local hcol 0..7
  const int hcol = (w << 3) | ej;

  const float pbi = bi[hcol], pbf = bfv[hcol], pbo = bo[hcol], pbc = bc[hcol];
  float Creg = 0.f;

  const int r0 = lane & 15;
  const int kq = (lane >> 4) * 8;

  // B fragments -> registers (weights resident for the whole scan)
  short8 bfrag[8][2];
  {
    #pragma unroll
    for (int ks = 0; ks < 8; ++ks) {
      int kb = (ks < 4) ? (wv * 128 + ks * 32 + kq)
                        : (DH + wv * 128 + (ks - 4) * 32 + kq);
      #pragma unroll
      for (int ni = 0; ni < 2; ++ni) {
        int col = ni * 16 + r0;
        bfrag[ks][ni] = *(const short8*)(Bws + ((size_t)(w * 32 + col) * KTOT + kb));
      }
    }
  }

  // stage x_0 -> As_x[0] (all threads)
  for (int g = tid; g < 4096; g += TPB) {
    int row = g >> 7, cc = g & 127;
    float4 v = *(const float4*)(x + (size_t)row * (S_ * DIN) + cc * 4);
    uint2 p;
    p.x = (unsigned)f2bf(v.x) | ((unsigned)f2bf(v.y) << 16);
    p.y = (unsigned)f2bf(v.z) | ((unsigned)f2bf(v.w) << 16);
    *(uint2*)(&As_x[0][row * XST + cc * 4]) = p;
  }
  __syncthreads();

  // x-part MFMA for t=0
  f32x4 acc00 = {0,0,0,0}, acc01 = {0,0,0,0}, acc10 = {0,0,0,0}, acc11 = {0,0,0,0};
  #pragma unroll
  for (int ks = 0; ks < 4; ++ks) {
    int koff = wv * 128 + ks * 32 + kq;
    short8 a0 = *(const short8*)(&As_x[0][r0 * XST + koff]);
    short8 a1 = *(const short8*)(&As_x[0][(r0 + 16) * XST + koff]);
    acc00 = mfma16(a0, bfrag[4 + ks][0], acc00);
    acc01 = mfma16(a0, bfrag[4 + ks][1], acc01);
    acc10 = mfma16(a1, bfrag[4 + ks][0], acc10);
    acc11 = mfma16(a1, bfrag[4 + ks][1], acc11);
  }

  for (int t = 0; t < S_; ++t) {
    __syncthreads();   // loop-top: orders prev Phase-E As_x reads vs new staging

    // ---- Phase P: wave0 polls its PRIVATE mailbox row; waves1-3 stage x_{t+1} ----
    if (wv == 0) {
      if (t > 0) {
        const int target = t - 1;
        int v = (int)__hip_atomic_load(&mbox[w * 64 + lane],
                                       __ATOMIC_RELAXED, __HIP_MEMORY_SCOPE_AGENT);
        while (__ballot(v < target)) {
          v = (int)__hip_atomic_load(&mbox[w * 64 + lane],
                                     __ATOMIC_RELAXED, __HIP_MEMORY_SCOPE_AGENT);
        }
      }
    } else if (t + 1 < S_) {
      int buf = (t + 1) & 1;
      for (int g = tid - 64; g < 4096; g += 192) {
        int row = g >> 7, cc = g & 127;
        float4 v = *(const float4*)(x + (size_t)row * (S_ * DIN) + (size_t)(t + 1) * DIN + cc * 4);
        uint2 p;
        p.x = (unsigned)f2bf(v.x) | ((unsigned)f2bf(v.y) << 16);
        p.y = (unsigned)f2bf(v.z) | ((unsigned)f2bf(v.w) << 16);
        *(uint2*)(&As_x[buf][row * XST + cc * 4]) = p;
      }
    }
    __syncthreads();

    // ---- Phase L: bulk-load H_{t-1} (coalesced, exactly once) -> Ah ----
    if (t > 0) {
      const u64* hr = hbuf + (size_t)((t - 1) & 1) * HBQ;
      u64 tmp[16];
      #pragma unroll
      for (int i = 0; i < 16; ++i) tmp[i] = cload(&hr[tid + i * TPB]);
      #pragma unroll
      for (int i = 0; i < 16; ++i) {
        int j = tid + i * TPB;
        int pw = j >> 6, r = j & 63;
        int b = r >> 1, h = r & 1;
        *(u64*)(&Ah[b * HST + pw * 8 + h * 4]) = tmp[i];
      }
    }
    __syncthreads();

    // ---- Phase M: H-part MFMA ----
    if (t > 0) {
      #pragma unroll
      for (int ks = 0; ks < 4; ++ks) {
        int koff = wv * 128 + ks * 32 + kq;
        short8 a0 = *(const short8*)(&Ah[r0 * HST + koff]);
        short8 a1 = *(const short8*)(&Ah[(r0 + 16) * HST + koff]);
        acc00 = mfma16(a0, bfrag[ks][0], acc00);
        acc01 = mfma16(a0, bfrag[ks][1], acc01);
        acc10 = mfma16(a1, bfrag[ks][0], acc10);
        acc11 = mfma16(a1, bfrag[ks][1], acc11);
      }
    }

    {
      float* rp = &R[(wv * 64 + lane) * 16];
      *(f32x4*)(rp + 0)  = acc00;
      *(f32x4*)(rp + 4)  = acc01;
      *(f32x4*)(rp + 8)  = acc10;
      *(f32x4*)(rp + 12) = acc11;
    }
    __syncthreads();

    // ---- Phase C: elementwise gates ----
    float pre[4];
    {
      int r = eb & 15, mi = eb >> 4, reg = eb & 3;
      int lq = (r >> 2) * 16;
      #pragma unroll
      for (int g = 0; g < 4; ++g) {
        int c  = g * 8 + ej;
        int ni = c >> 4;
        int ln = (c & 15) + lq;
        int idx = (mi * 2 + ni) * 4 + reg;
        float s = 0.f;
        #pragma unroll
        for (int v = 0; v < 4; ++v) s += R[(v * 64 + ln) * 16 + idx];
        pre[g] = s;
      }
    }
    float I  = sigmoid_f(pre[0] + pbi);
    float F  = sigmoid_f(pre[1] + pbf);
    float O  = sigmoid_f(pre[2] + pbo);
    float Cc = tanh_f(pre[3] + pbc);
    Creg = F * Creg + I * Cc;
    float H = O * tanh_f(Creg);

    out[(size_t)eb * (S_ * DH) + (size_t)t * DH + hcol] = H;
    if (t == S_ - 1) out[(size_t)(B_ * S_ * DH) + eb * DH + hcol] = H;  // Hf
    Hs[tid] = f2bf(H);
    __syncthreads();

    // ---- Phase D: publish (wave0): data burst -> drain -> epoch to all mailboxes ----
    if (wv == 0 && t + 1 < S_) {
      int b = lane >> 1, h = lane & 1;
      u64 v = (u64)Hs[b * 8 + h * 4]
            | ((u64)Hs[b * 8 + h * 4 + 1] << 16)
            | ((u64)Hs[b * 8 + h * 4 + 2] << 32)
            | ((u64)Hs[b * 8 + h * 4 + 3] << 48);
      cstore(&hbuf[(size_t)(t & 1) * HBQ + w * 64 + lane], v);
      __asm__ volatile("s_waitcnt vmcnt(0)" ::: "memory");   // data at LLC
      __hip_atomic_store(&mbox[lane * 64 + w], t,
                         __ATOMIC_RELAXED, __HIP_MEMORY_SCOPE_AGENT);
    }

    // ---- Phase E: x-part MFMA for t+1 ----
    if (t + 1 < S_) {
      acc00 = (f32x4){0,0,0,0}; acc01 = (f32x4){0,0,0,0};
      acc10 = (f32x4){0,0,0,0}; acc11 = (f32x4){0,0,0,0};
      int buf = (t + 1) & 1;
      #pragma unroll
      for (int ks = 0; ks < 4; ++ks) {
        int koff = wv * 128 + ks * 32 + kq;
        short8 a0 = *(const short8*)(&As_x[buf][r0 * XST + koff]);
        short8 a1 = *(const short8*)(&As_x[buf][(r0 + 16) * XST + koff]);
        acc00 = mfma16(a0, bfrag[4 + ks][0], acc00);
        acc01 = mfma16(a0, bfrag[4 + ks][1], acc01);
        acc10 = mfma16(a1, bfrag[4 + ks][0], acc10);
        acc11 = mfma16(a1, bfrag[4 + ks][1], acc11);
      }
    }
  }
}

extern "C" void kernel_launch(void* const* d_in, const int* in_sizes, int n_in,
                              void* d_out, int out_size, void* d_ws, size_t ws_size,
                              hipStream_t stream) {
  const float* x   = (const float*)d_in[0];
  const float* Wxi = (const float*)d_in[1];
  const float* Whi = (const float*)d_in[2];
  const float* bi  = (const float*)d_in[3];
  const float* Wxf = (const float*)d_in[4];
  const float* Whf = (const float*)d_in[5];
  const float* bfv = (const float*)d_in[6];
  const float* Wxo = (const float*)d_in[7];
  const float* Who = (const float*)d_in[8];
  const float* bo  = (const float*)d_in[9];
  const float* Wxc = (const float*)d_in[10];
  const float* Whc = (const float*)d_in[11];
  const float* bc  = (const float*)d_in[12];
  float* out = (float*)d_out;

  // ws layout: Bws 4 MiB | hbuf 64 KiB (2 buffers) | mbox 16 KiB
  unsigned short* Bws  = (unsigned short*)d_ws;
  u64*            hbuf = (u64*)((char*)d_ws + (size_t)4 * 1024 * 1024);
  int*            mbox = (int*)((char*)d_ws + (size_t)4 * 1024 * 1024 + 64 * 1024);

  k_prep<<<1024, TPB, 0, stream>>>(Whi, Whf, Who, Whc, Wxi, Wxf, Wxo, Wxc, Bws, mbox);
  k_scan<<<NWG, TPB, 0, stream>>>(x, bi, bfv, bo, bc, Bws, hbuf, mbox, out);
}